// Round 4
// baseline (187.026 us; speedup 1.0000x reference)
//
#include <hip/hip_runtime.h>

// Loss_8615704396494: masked L1 + 0.1 * bone-direction MSE over [B=128,T=1024,150] fp32.
// Memory-bound (157.3 MB read, scalar out).
//
// R8 (re-run; previous attempt died to container infra, not kernel): no LDS.
// R5 (lockstep), R6 (wave-private LDS), R7 (2x occupancy) ALL delivered
// 2.5 TB/s / ~60-63 us with every pipe idle -> the common factor is the LDS
// round-trip (global->reg->ds_write->scalar ds_read->VALU) serializing each wave's
// iteration on vmcnt/lgkmcnt chains (R7's 32-VGPR allocation also serialized the
// prefetch). The chip streams 6.3 TB/s (D2D copy), so 2.5 is structural, not HW.
// New mapping: lane = joint. A wave processes one 150-float row per iteration:
// lane l (0..49) loads joint l's 3 floats from each array (contiguous 600 B/row,
// L1 absorbs the 12B-stride component access), masks in registers, and the bone's
// dst joint comes from ONE __shfl to lane (l+1)%50. Lanes 50..63 idle (masked to
// zero contribution). No LDS, no barriers, no bank conflicts. 1-row register
// prefetch; __launch_bounds__(256,8) -> 32 waves/CU (no LDS cap).
// 8192 waves x 16 rows = 131072 rows exactly.

#define ROW_F    150
#define N_JOINT  50
#define GRID     2048
#define WAVES_PB 4
#define TOTAL_WAVES (GRID * WAVES_PB)   // 8192 waves; 131072 rows -> iters = 16

__global__ __launch_bounds__(256, 8) void loss_kernel(
    const float* __restrict__ preds,
    const float* __restrict__ targets,
    float* __restrict__ out,
    int iters, float inv_count)
{
    const float EPS = 1e-8f;
    __shared__ float wsum[WAVES_PB];

    const int tid  = threadIdx.x;
    const int lane = tid & 63;
    const int wid  = tid >> 6;
    const bool act = (lane < N_JOINT);
    const int  sel = (lane + 1 == N_JOINT) ? 0 : lane + 1;   // lane holding dst joint

    const int wglobal = blockIdx.x * WAVES_PB + wid;
    const ptrdiff_t STRIDE = (ptrdiff_t)TOTAL_WAVES * ROW_F;

    // Per-lane element offset inside a row (clamped for idle lanes; their values
    // are forced to zero contribution below, and the clamp keeps loads in-bounds).
    const int eoff = act ? 3 * lane : 0;

    const float* pp = preds   + (size_t)wglobal * ROW_F + eoff;
    const float* tp = targets + (size_t)wglobal * ROW_F + eoff;

    float l1 = 0.f, mse = 0.f;

    // Prologue: load row 0's joint
    float cp0 = pp[0], cp1 = pp[1], cp2 = pp[2];
    float ct0 = tp[0], ct1 = tp[1], ct2 = tp[2];
    pp += STRIDE; tp += STRIDE;

    for (int it = 0; it < iters; ++it) {
        // Prefetch next row (in flight across this row's compute).
        float np0 = 0.f, np1 = 0.f, np2 = 0.f, nt0 = 0.f, nt1 = 0.f, nt2 = 0.f;
        if (it + 1 < iters) {                      // uniform branch
            np0 = pp[0]; np1 = pp[1]; np2 = pp[2];
            nt0 = tp[0]; nt1 = tp[1]; nt2 = tp[2];
            pp += STRIDE; tp += STRIDE;
        }

        // Masked src joint (this lane's joint). Idle lanes: tm=0 -> zero everywhere.
        float tm0 = act ? ct0 : 0.f;
        float tm1 = act ? ct1 : 0.f;
        float tm2 = act ? ct2 : 0.f;
        float pm0 = (tm0 != 0.f) ? cp0 : 0.f;
        float pm1 = (tm1 != 0.f) ? cp1 : 0.f;
        float pm2 = (tm2 != 0.f) ? cp2 : 0.f;

        l1 += fabsf(pm0 - tm0) + fabsf(pm1 - tm1) + fabsf(pm2 - tm2);

        // Dst joint from neighbor lane (sources are always lanes 0..49, which
        // hold valid masked values).
        float pn0 = __shfl(pm0, sel, 64);
        float pn1 = __shfl(pm1, sel, 64);
        float pn2 = __shfl(pm2, sel, 64);
        float tn0 = __shfl(tm0, sel, 64);
        float tn1 = __shfl(tm1, sel, 64);
        float tn2 = __shfl(tm2, sel, 64);

        float dp0 = pm0 - pn0, dp1 = pm1 - pn1, dp2 = pm2 - pn2;
        float dt0 = tm0 - tn0, dt1 = tm1 - tn1, dt2 = tm2 - tn2;
        float lp = dp0 * dp0 + dp1 * dp1 + dp2 * dp2;
        float lt = dt0 * dt0 + dt1 * dt1 + dt2 * dt2;
        float ip = __builtin_amdgcn_rcpf(__builtin_amdgcn_sqrtf(lp) + EPS);
        float iq = __builtin_amdgcn_rcpf(__builtin_amdgcn_sqrtf(lt) + EPS);

        // Direction diff, masked by the src joint's component mask (tm_c != 0).
        float d0 = dp0 * ip - dt0 * iq; d0 = (tm0 != 0.f) ? d0 : 0.f;
        float d1 = dp1 * ip - dt1 * iq; d1 = (tm1 != 0.f) ? d1 : 0.f;
        float d2 = dp2 * ip - dt2 * iq; d2 = (tm2 != 0.f) ? d2 : 0.f;
        mse += d0 * d0 + d1 * d1 + d2 * d2;

        cp0 = np0; cp1 = np1; cp2 = np2;
        ct0 = nt0; ct1 = nt1; ct2 = nt2;
    }

    // ---- Reduce: loss = (l1 + 0.1*mse) / COUNT ----
    float part = (l1 + 0.1f * mse) * inv_count;
#pragma unroll
    for (int off = 32; off > 0; off >>= 1)
        part += __shfl_down(part, off, 64);

    if (lane == 0) wsum[wid] = part;
    __syncthreads();                        // only barrier in the kernel
    if (tid == 0) {
        atomicAdd(out, wsum[0] + wsum[1] + wsum[2] + wsum[3]);
    }
}

extern "C" void kernel_launch(void* const* d_in, const int* in_sizes, int n_in,
                              void* d_out, int out_size, void* d_ws, size_t ws_size,
                              hipStream_t stream)
{
    const float* preds   = (const float*)d_in[0];
    const float* targets = (const float*)d_in[1];
    float* out = (float*)d_out;

    // d_out is re-poisoned to 0xAA before every timed launch — zero it (capture-safe).
    hipMemsetAsync(out, 0, sizeof(float) * out_size, stream);

    int n_elems = in_sizes[0];              // 128*1024*150 = 19,660,800
    int n_rows  = n_elems / ROW_F;          // 131072
    float inv_count = 1.0f / (float)n_elems;

    int iters = n_rows / TOTAL_WAVES;       // 16
    loss_kernel<<<GRID, 256, 0, stream>>>(preds, targets, out, iters, inv_count);
}

// Round 6
// 164.195 us; speedup vs baseline: 1.1390x; 1.1390x over previous
//
#include <hip/hip_runtime.h>

// Loss_8615704396494: masked L1 + 0.1 * bone-direction MSE over [B=128,T=1024,150] fp32.
// Memory-bound (157.3 MB read once, scalar out). Irreducible traffic: both arrays
// fully read (L1 needs p,t; MSE needs bone directions of both).
//
// R9 = R6 (best, 60 us) + NON-TEMPORAL loads. Single-lever A/B.
// (resubmit: __builtin_nontemporal_load needs a native ext_vector_type pointer,
//  not HIP_vector_type<float,4> -> load via float ext_vector_type(4).)
// Evidence so far: R5/R6/R7/R8 (4 schedules, occupancy 16->32 w/CU, with/without
// LDS) all pin at 2.2-2.6 TB/s delivered with no pipe saturated -> consistent with
// a per-CU outstanding-miss (MSHR) ceiling on the streaming-read path
// (~copy's read stream = 3.15 TB/s; we're at 83% of it). Zero reuse in this
// problem -> nt loads are semantically free; testing whether the nt allocation
// path lifts the streaming ceiling.
// Structure (unchanged from R6): each WAVE owns a private 9.6 KB LDS slice
// (8 rows x 150 f x 2 arrays): stage own span -> L1 from regs -> prefetch next
// span -> bone MSE from LDS. No barriers in the main loop (same-wave LDS ops
// in-order; ds_reads consumed before next iteration's ds_writes).

#define ROW_F    150
#define ROWS_PW  8                    // rows per wave-span
#define SPAN_F   (ROWS_PW * ROW_F)    // 1200 floats per array per wave-span
#define SPAN_F4  (SPAN_F / 4)         // 300 float4
#define WAVES_PB 4
#define GRID     1024
#define TOTAL_WAVES (GRID * WAVES_PB) // 4096 waves; 16384 spans -> iters = 4

typedef float f4 __attribute__((ext_vector_type(4)));

#define NTL(p) __builtin_nontemporal_load(&(p))

__global__ __launch_bounds__(256, 4) void loss_kernel(
    const float* __restrict__ preds,
    const float* __restrict__ targets,
    float* __restrict__ out,
    int iters, float inv_count)
{
    const float EPS = 1e-8f;
    __shared__ float sp[WAVES_PB][SPAN_F];
    __shared__ float st[WAVES_PB][SPAN_F];
    __shared__ float wsum[WAVES_PB];

    const int tid  = threadIdx.x;
    const int lane = tid & 63;
    const int wid  = tid >> 6;

    const f4* gp4 = reinterpret_cast<const f4*>(preds);
    const f4* gt4 = reinterpret_cast<const f4*>(targets);
    f4* sp4 = reinterpret_cast<f4*>(sp[wid]);
    f4* st4 = reinterpret_cast<f4*>(st[wid]);

    // Per-lane float4 slots within the wave's 300-float4 span: 4 full + 1 tail.
    const int g0 = lane, g1 = lane + 64, g2 = lane + 128, g3 = lane + 192, g4 = lane + 256;
    const bool w4 = (g4 < SPAN_F4);          // lane < 44
    const int g4c = w4 ? g4 : (SPAN_F4 - 1); // clamped (uniform flow, stays in VGPRs)

    // Compute mapping inside the wave: 8 rows x 8 segments.
    const int row = lane >> 3;               // 0..7
    const int seg = lane & 7;                // 0..7
    const int j0 = (seg < 2) ? seg * 7 : 14 + (seg - 2) * 6;  // segs 0,1: 7 bones; else 6
    const int j1 = (seg < 2) ? j0 + 7 : j0 + 6;

    float l1 = 0.0f, mse = 0.0f;

    const int wglobal = blockIdx.x * WAVES_PB + wid;

    // Prologue prefetch: span = wglobal
    size_t sb = (size_t)wglobal * SPAN_F4;
    f4 rp0 = NTL(gp4[sb + g0]), rp1 = NTL(gp4[sb + g1]), rp2 = NTL(gp4[sb + g2]),
       rp3 = NTL(gp4[sb + g3]), rp4 = NTL(gp4[sb + g4c]);
    f4 rt0 = NTL(gt4[sb + g0]), rt1 = NTL(gt4[sb + g1]), rt2 = NTL(gt4[sb + g2]),
       rt3 = NTL(gt4[sb + g3]), rt4 = NTL(gt4[sb + g4c]);

#define L1ACC(P, T) do {                                             \
        l1 += ((T).x != 0.0f) ? fabsf((P).x - (T).x) : 0.0f;         \
        l1 += ((T).y != 0.0f) ? fabsf((P).y - (T).y) : 0.0f;         \
        l1 += ((T).z != 0.0f) ? fabsf((P).z - (T).z) : 0.0f;         \
        l1 += ((T).w != 0.0f) ? fabsf((P).w - (T).w) : 0.0f;         \
    } while (0)

    for (int it = 0; it < iters; ++it) {
        // regs -> private LDS slice (compiler inserts counted vmcnt waits here)
        sp4[g0] = rp0; st4[g0] = rt0;
        sp4[g1] = rp1; st4[g1] = rt1;
        sp4[g2] = rp2; st4[g2] = rt2;
        sp4[g3] = rp3; st4[g3] = rt3;
        if (w4) { sp4[g4] = rp4; st4[g4] = rt4; }

        // L1 term directly from the registers (must precede the prefetch overwrite).
        L1ACC(rp0, rt0); L1ACC(rp1, rt1); L1ACC(rp2, rt2); L1ACC(rp3, rt3);
        if (w4) L1ACC(rp4, rt4);

        // Issue next span's loads; in flight during the bone compute below.
        if (it + 1 < iters) {
            size_t nb = (size_t)(wglobal + (size_t)(it + 1) * TOTAL_WAVES) * SPAN_F4;
            rp0 = NTL(gp4[nb + g0]); rp1 = NTL(gp4[nb + g1]); rp2 = NTL(gp4[nb + g2]);
            rp3 = NTL(gp4[nb + g3]); rp4 = NTL(gp4[nb + g4c]);
            rt0 = NTL(gt4[nb + g0]); rt1 = NTL(gt4[nb + g1]); rt2 = NTL(gt4[nb + g2]);
            rt3 = NTL(gt4[nb + g3]); rt4 = NTL(gt4[nb + g4c]);
        }

        // ---- Bone-direction MSE from the private LDS slice ----
        const float* rpb = &sp[wid][row * ROW_F];
        const float* rtb = &st[wid][row * ROW_F];

        float pmP[3], tmP[3];
#pragma unroll
        for (int c = 0; c < 3; ++c) {
            float t = rtb[3 * j0 + c];
            float p = rpb[3 * j0 + c];
            pmP[c] = (t != 0.0f) ? p : 0.0f;   // masked pred
            tmP[c] = t;                        // masked target == target
        }

        for (int b = j0; b < j1; ++b) {
            int jn = b + 1;
            if (jn == 50) jn = 0;              // wrap bone (seg 7), wave-uniform
            float pmN[3], tmN[3];
#pragma unroll
            for (int c = 0; c < 3; ++c) {
                float t = rtb[3 * jn + c];
                float p = rpb[3 * jn + c];
                pmN[c] = (t != 0.0f) ? p : 0.0f;
                tmN[c] = t;
            }
            float dp[3], dt[3], lp = 0.0f, lt = 0.0f;
#pragma unroll
            for (int c = 0; c < 3; ++c) {
                dp[c] = pmP[c] - pmN[c];
                dt[c] = tmP[c] - tmN[c];
                lp += dp[c] * dp[c];
                lt += dt[c] * dt[c];
            }
            float ip = __builtin_amdgcn_rcpf(__builtin_amdgcn_sqrtf(lp) + EPS);
            float iq = __builtin_amdgcn_rcpf(__builtin_amdgcn_sqrtf(lt) + EPS);
#pragma unroll
            for (int c = 0; c < 3; ++c) {
                float d = dp[c] * ip - dt[c] * iq;
                d = (tmP[c] != 0.0f) ? d : 0.0f;   // source-joint mask
                mse += d * d;
            }
#pragma unroll
            for (int c = 0; c < 3; ++c) { pmP[c] = pmN[c]; tmP[c] = tmN[c]; }
        }
    }

    // ---- Reduce: loss = (l1 + 0.1*mse) / COUNT ----
    float part = (l1 + 0.1f * mse) * inv_count;
#pragma unroll
    for (int off = 32; off > 0; off >>= 1)
        part += __shfl_down(part, off, 64);

    if (lane == 0) wsum[wid] = part;
    __syncthreads();                        // only barrier in the kernel
    if (tid == 0) {
        atomicAdd(out, wsum[0] + wsum[1] + wsum[2] + wsum[3]);
    }
}

extern "C" void kernel_launch(void* const* d_in, const int* in_sizes, int n_in,
                              void* d_out, int out_size, void* d_ws, size_t ws_size,
                              hipStream_t stream)
{
    const float* preds   = (const float*)d_in[0];
    const float* targets = (const float*)d_in[1];
    float* out = (float*)d_out;

    // d_out is re-poisoned to 0xAA before every timed launch — zero it (capture-safe).
    hipMemsetAsync(out, 0, sizeof(float) * out_size, stream);

    int n_elems = in_sizes[0];              // 128*1024*150 = 19,660,800
    int n_rows  = n_elems / ROW_F;          // 131072
    int spans   = n_rows / ROWS_PW;         // 16384
    float inv_count = 1.0f / (float)n_elems;

    int iters = spans / TOTAL_WAVES;        // 4
    loss_kernel<<<GRID, 256, 0, stream>>>(preds, targets, out, iters, inv_count);
}